// Round 3
// baseline (4135.427 us; speedup 1.0000x reference)
//
#include <hip/hip_runtime.h>

typedef float f2 __attribute__((ext_vector_type(2)));

#define NB 4
#define NN 4096
#define KNB 16
#define NS 1024
#define M1TOT (NB*NN*KNB)   // 262144
#define EPSBN 1e-5f
#define FPS_E0 255          // kPre runs iters [0, 255)
#define FPS_E1 639          // kS1 runs [255, 639); kS2 runs [639, 1023)

// ---- module-scope scratch (fully rewritten every call; no ws_size assumption)
__device__ __align__(16) float g_h1[M1TOT*128];        // 134 MB spilled layer-1 pre-activations
__device__ __align__(16) int   g_nbr[NB*NN*KNB];
__device__ __align__(16) float g_fps_rd[NB][NN];
__device__ unsigned g_fps_sel[NB][256];
__device__ int   g_fps_last[NB];
__device__ int   g_cent[NB][NS];
__device__ float g_sum1[128], g_sq1[128], g_sum2[128], g_sq2[128];
__device__ __align__(16) float g_hminN[NB*NN*128];     // 8 MB per-node h2 min
__device__ __align__(16) float g_hmaxN[NB*NN*128];     // 8 MB per-node h2 max

struct __align__(16) FpsSm {
    float spx[NN], spy[NN], spz[NN];
    float sv[2][4]; int sj[2][4];
    int   cnts[256];
};
struct __align__(16) G1Sm {
    float  xls[64*68];
    float4 wlsA[68*16], wlsB[68*16];
    float  redS[512], redQ[512];
};
struct __align__(16) G2Sm {
    float  yls[64*132];
    float4 w2A[32*16], w2B[32*16];
    float  scs[128], shs[128];
    float  redS[512], redQ[512];
};

// ================= FPS chunk: 256 threads, 16 pts/thread, checkpointed =================
__device__ __forceinline__ void fps_chunk(const float* __restrict__ pos, float* __restrict__ out,
                                          FpsSm* sm, int b, int t, int it0, int it1,
                                          bool first, bool last)
{
#pragma clang fp contract(off)
    const float* pb = pos + b*NN*3;
    for (int i = t; i < NN; i += 256) { sm->spx[i]=pb[3*i]; sm->spy[i]=pb[3*i+1]; sm->spz[i]=pb[3*i+2]; }
    __syncthreads();
    f2 rx[8], ry[8], rz[8], rd[8];
    #pragma unroll
    for (int p=0;p<8;p++){
        int j = (t<<4) + 2*p;
        rx[p] = (f2){sm->spx[j], sm->spx[j+1]};
        ry[p] = (f2){sm->spy[j], sm->spy[j+1]};
        rz[p] = (f2){sm->spz[j], sm->spz[j+1]};
    }
    unsigned sel; int j2;
    if (first) {
        #pragma unroll
        for (int p=0;p<8;p++) rd[p] = (f2){1e10f, 1e10f};
        sel = (t==0) ? 1u : 0u;
        j2 = 0;
    } else {
        #pragma unroll
        for (int u=0;u<4;u++){
            float4 ld = *(const float4*)&g_fps_rd[b][(t<<4)+(u<<2)];
            rd[2*u]   = (f2){ld.x, ld.y};
            rd[2*u+1] = (f2){ld.z, ld.w};
        }
        sel = g_fps_sel[b][t];
        j2  = g_fps_last[b];
    }
    float cx = sm->spx[j2], cy = sm->spy[j2], cz = sm->spz[j2];
    const int lane = t & 63, wid = t >> 6;

    for (int it = it0; it < it1; ++it) {
        const int par = it & 1;
        f2 c2x = {cx,cx}, c2y = {cy,cy}, c2z = {cz,cz};
        f2 bv2 = {-1.f,-1.f};
        #pragma unroll
        for (int p=0;p<8;p++){
            f2 dx = rx[p]-c2x, dy = ry[p]-c2y, dz = rz[p]-c2z;
            f2 m0 = dx*dx, m1 = dy*dy, m2 = dz*dz;
            f2 a0 = m0 + m1;
            f2 d  = a0 + m2;                       // exact (dx^2+dy^2)+dz^2, contract off
            rd[p] = __builtin_elementwise_min(rd[p], d);
            bv2   = __builtin_elementwise_max(bv2, rd[p]);
        }
        float bv = fmaxf(bv2.x, bv2.y);
        int bj = 0;
        #pragma unroll
        for (int p=7;p>=0;p--){                    // reverse scan -> lowest matching index
            bj = (rd[p].y == bv) ? ((t<<4)+2*p+1) : bj;
            bj = (rd[p].x == bv) ? ((t<<4)+2*p)   : bj;
        }
        #pragma unroll
        for (int m=1;m<64;m<<=1){                  // wave argmax (value desc, index asc)
            float ov = __shfl_xor(bv, m);
            int   oj = __shfl_xor(bj, m);
            if (ov > bv || (ov == bv && oj < bj)) { bv = ov; bj = oj; }
        }
        if (lane == 0) { sm->sv[par][wid] = bv; sm->sj[par][wid] = bj; }
        __syncthreads();
        float v = sm->sv[par][0]; int jn = sm->sj[par][0];
        #pragma unroll
        for (int w=1;w<4;w++){
            float ov = sm->sv[par][w]; int oj = sm->sj[par][w];
            if (ov > v || (ov == v && oj < jn)) { v = ov; jn = oj; }
        }
        j2 = jn;
        cx = sm->spx[j2]; cy = sm->spy[j2]; cz = sm->spz[j2];
        unsigned rel = (unsigned)(j2 - (t<<4));
        if (rel < 16u) sel |= (1u << rel);
    }

    if (!last) {
        #pragma unroll
        for (int u=0;u<4;u++){
            float4 st = {rd[2*u].x, rd[2*u].y, rd[2*u+1].x, rd[2*u+1].y};
            *(float4*)&g_fps_rd[b][(t<<4)+(u<<2)] = st;
        }
        g_fps_sel[b][t] = sel;
        if (t == 0) g_fps_last[b] = j2;
    } else {
        sm->cnts[t] = (int)__popc(sel);
        __syncthreads();
        if (t == 0) { int run = 0; for (int i=0;i<256;i++){ int c = sm->cnts[i]; sm->cnts[i] = run; run += c; } }
        __syncthreads();
        int base = sm->cnts[t];
        #pragma unroll
        for (int i=0;i<16;i++){
            int j = (t<<4)+i;
            if (sel & (1u<<i)) {
                g_cent[b][base] = j;
                float* po = out + (size_t)((b<<10)+base)*3;
                po[0]=sm->spx[j]; po[1]=sm->spy[j]; po[2]=sm->spz[j];
                base++;
            }
        }
    }
}

__device__ __forceinline__ void knn_ins(float (&bd)[16], int (&bi)[16], float &wmax, float d, int j)
{
    float m0 = bd[0]; int mj = 0;
    #pragma unroll
    for (int u=1;u<16;u++){ if (bd[u] > m0){ m0 = bd[u]; mj = u; } }
    #pragma unroll
    for (int u=0;u<16;u++){ if (u == mj){ bd[u] = d; bi[u] = j; } }
    float w = bd[0];
    #pragma unroll
    for (int u=1;u<16;u++) w = fmaxf(w, bd[u]);
    wmax = w;
}

// ================= kPre: blocks 0-3 FPS chunk A, 4-35 KNN (2q/thread), 36 zero =================
__global__ __launch_bounds__(256) void kPre(const float* __restrict__ pos)
{
#pragma clang fp contract(off)
    __shared__ FpsSm sm;
    const int blk = blockIdx.x, t = threadIdx.x;
    if (blk >= 36) {
        if (t < 128) { g_sum1[t]=0.f; g_sq1[t]=0.f; g_sum2[t]=0.f; g_sq2[t]=0.f; }
        return;
    }
    if (blk < 4) {
        fps_chunk(pos, nullptr, &sm, blk, t, 0, FPS_E0, true, false);
        return;
    }
    // ---- KNN: 32 blocks, 2 queries per thread, 2 candidates per LDS read ----
    const int kb = blk - 4;
    const int b = kb >> 3;
    const int q0 = ((kb & 7) << 9) + t;
    const int q1 = q0 + 256;
    const float* pb = pos + b*NN*3;
    for (int i = t; i < NN; i += 256) { sm.spx[i]=pb[3*i]; sm.spy[i]=pb[3*i+1]; sm.spz[i]=pb[3*i+2]; }
    __syncthreads();
    const float qx0=sm.spx[q0], qy0=sm.spy[q0], qz0=sm.spz[q0];
    const float qx1=sm.spx[q1], qy1=sm.spy[q1], qz1=sm.spz[q1];
    float bd0[16], bd1[16]; int bi0[16], bi1[16];
    #pragma unroll
    for (int u=0;u<16;u++){ bd0[u]=3e38f; bi0[u]=0; bd1[u]=3e38f; bi1[u]=0; }
    float wm0 = 3e38f, wm1 = 3e38f;
    const f2 v0x={qx0,qx0}, v0y={qy0,qy0}, v0z={qz0,qz0};
    const f2 v1x={qx1,qx1}, v1y={qy1,qy1}, v1z={qz1,qz1};
    for (int j = 0; j < NN; j += 2) {
        f2 px = *(const f2*)&sm.spx[j];
        f2 py = *(const f2*)&sm.spy[j];
        f2 pz = *(const f2*)&sm.spz[j];
        {
            f2 dx = px - v0x, dy = py - v0y, dz = pz - v0z;
            f2 m0 = dx*dx, m1 = dy*dy, m2 = dz*dz;
            f2 a0 = m0 + m1; f2 d = a0 + m2;
            if (d.x < wm0) knn_ins(bd0, bi0, wm0, d.x, j);
            if (d.y < wm0) knn_ins(bd0, bi0, wm0, d.y, j+1);
        }
        {
            f2 dx = px - v1x, dy = py - v1y, dz = pz - v1z;
            f2 m0 = dx*dx, m1 = dy*dy, m2 = dz*dz;
            f2 a0 = m0 + m1; f2 d = a0 + m2;
            if (d.x < wm1) knn_ins(bd1, bi1, wm1, d.x, j);
            if (d.y < wm1) knn_ins(bd1, bi1, wm1, d.y, j+1);
        }
    }
    int* dst0 = g_nbr + ((size_t)(b*NN + q0) << 4);
    int* dst1 = g_nbr + ((size_t)(b*NN + q1) << 4);
    #pragma unroll
    for (int u=0;u<16;u++){ dst0[u] = bi0[u]; dst1[u] = bi1[u]; }
}

// ================= kS1: blocks 0-3 FPS chunk B; blocks 4..4099 GEMM1 + stats + h1 spill ======
__global__ __launch_bounds__(256) void kS1(const float* __restrict__ feat, const float* __restrict__ pos,
                                           const float* __restrict__ W1, const float* __restrict__ b1)
{
    __shared__ union { FpsSm f; G1Sm g; } sm;
    const int blk = blockIdx.x, t = threadIdx.x;
    if (blk < 4) { fps_chunk(pos, nullptr, &sm.f, blk, t, FPS_E0, FPS_E1, false, false); return; }
    const int gb = blk - 4;
    const int b = gb >> 10, nb = (gb & 1023) << 2;

    // stage W1 -> two float4 arrays [row 0..67][cg], row permuted (feat 0..63, rel 64..66, 67 zero)
    for (int e = t; e < 128*67; e += 256) {
        int co = e / 67, ci = e - co*67;
        int row = (ci < 3) ? (64 + ci) : (ci - 3);
        int cgd = co >> 3, h = co & 7;
        float w = W1[e];
        if (h < 4) ((float*)&sm.g.wlsA[row*16 + cgd])[h]   = w;
        else       ((float*)&sm.g.wlsB[row*16 + cgd])[h-4] = w;
    }
    if (t < 64) { ((float*)&sm.g.wlsA[67*16])[t] = 0.f; ((float*)&sm.g.wlsB[67*16])[t] = 0.f; }
    // gather x: 64 samples (4 nodes x 16 nbrs) x 68
    {
        const int s = t >> 2, h = t & 3;
        const int n = nb + (s >> 4), k = s & 15;
        const int gq = b*NN + n;
        const int idx = g_nbr[(gq << 4) + k];
        const float* fr = feat + ((size_t)(b*NN + idx) << 6) + (h << 4);
        float* xr = sm.g.xls + s*68 + (h << 4);
        #pragma unroll
        for (int u=0;u<4;u++) ((float4*)xr)[u] = ((const float4*)fr)[u];
        if (h == 0) {
            const float* pn = pos + (size_t)gq*3;
            const float* pi = pos + (size_t)(b*NN + idx)*3;
            sm.g.xls[s*68 + 64] = pi[0]-pn[0];
            sm.g.xls[s*68 + 65] = pi[1]-pn[1];
            sm.g.xls[s*68 + 66] = pi[2]-pn[2];
            sm.g.xls[s*68 + 67] = 0.f;
        }
    }
    __syncthreads();
    const int cg = t & 15, sg = t >> 4, w = t >> 6;
    float acc[4][8];
    #pragma unroll
    for (int r=0;r<4;r++)
        #pragma unroll
        for (int c=0;c<8;c++) acc[r][c] = 0.f;
    for (int c4 = 0; c4 < 17; ++c4) {
        float4 wA[4], wB[4];
        #pragma unroll
        for (int ii=0;ii<4;ii++){ wA[ii] = sm.g.wlsA[(4*c4+ii)*16 + cg]; wB[ii] = sm.g.wlsB[(4*c4+ii)*16 + cg]; }
        #pragma unroll
        for (int r=0;r<4;r++){
            float4 xv = *(const float4*)&sm.g.xls[(sg + (r<<4))*68 + (c4<<2)];
            #pragma unroll
            for (int ii=0;ii<4;ii++){
                float x = (ii==0)?xv.x:(ii==1)?xv.y:(ii==2)?xv.z:xv.w;
                acc[r][0] = fmaf(x, wA[ii].x, acc[r][0]);
                acc[r][1] = fmaf(x, wA[ii].y, acc[r][1]);
                acc[r][2] = fmaf(x, wA[ii].z, acc[r][2]);
                acc[r][3] = fmaf(x, wA[ii].w, acc[r][3]);
                acc[r][4] = fmaf(x, wB[ii].x, acc[r][4]);
                acc[r][5] = fmaf(x, wB[ii].y, acc[r][5]);
                acc[r][6] = fmaf(x, wB[ii].z, acc[r][6]);
                acc[r][7] = fmaf(x, wB[ii].w, acc[r][7]);
            }
        }
    }
    // h1 = acc + b1 ; stats ; spill to g_h1
    float4 bA = *(const float4*)&b1[cg<<3];
    float4 bB = *(const float4*)&b1[(cg<<3)+4];
    float h1v[4][8];
    #pragma unroll
    for (int r=0;r<4;r++){
        h1v[r][0]=acc[r][0]+bA.x; h1v[r][1]=acc[r][1]+bA.y; h1v[r][2]=acc[r][2]+bA.z; h1v[r][3]=acc[r][3]+bA.w;
        h1v[r][4]=acc[r][4]+bB.x; h1v[r][5]=acc[r][5]+bB.y; h1v[r][6]=acc[r][6]+bB.z; h1v[r][7]=acc[r][7]+bB.w;
    }
    #pragma unroll
    for (int c=0;c<8;c++){
        const int ch = (cg<<3)+c;
        float ls=0.f, lq=0.f;
        #pragma unroll
        for (int r=0;r<4;r++){ float h1 = h1v[r][c]; ls += h1; lq = fmaf(h1,h1,lq); }
        ls += __shfl_xor(ls,16); ls += __shfl_xor(ls,32);
        lq += __shfl_xor(lq,16); lq += __shfl_xor(lq,32);
        if ((sg & 3) == 0) { sm.g.redS[w*128 + ch] = ls; sm.g.redQ[w*128 + ch] = lq; }
    }
    #pragma unroll
    for (int r=0;r<4;r++){
        const int gs = (b*NN + nb + r)*16 + sg;
        float4 o0 = {h1v[r][0],h1v[r][1],h1v[r][2],h1v[r][3]};
        float4 o1 = {h1v[r][4],h1v[r][5],h1v[r][6],h1v[r][7]};
        *(float4*)&g_h1[gs*128 + (cg<<3)]     = o0;
        *(float4*)&g_h1[gs*128 + (cg<<3) + 4] = o1;
    }
    __syncthreads();
    if (t < 128) {
        float s = sm.g.redS[t] + sm.g.redS[128+t] + sm.g.redS[256+t] + sm.g.redS[384+t];
        float q = sm.g.redQ[t] + sm.g.redQ[128+t] + sm.g.redQ[256+t] + sm.g.redQ[384+t];
        atomicAdd(&g_sum1[t], s);
        atomicAdd(&g_sq1[t], q);
    }
}

// ================= kS2: blocks 0-3 FPS chunk C (finish); blocks 4..4099 BN1+GEMM2 ============
__global__ __launch_bounds__(256) void kS2(const float* __restrict__ pos, float* __restrict__ out,
        const float* __restrict__ W2, const float* __restrict__ b2,
        const float* __restrict__ gamma1, const float* __restrict__ beta1)
{
    __shared__ union { FpsSm f; G2Sm g; } sm;
    const int blk = blockIdx.x, t = threadIdx.x;
    if (blk < 4) { fps_chunk(pos, out, &sm.f, blk, t, FPS_E1, NS-1, false, true); return; }
    const int gb = blk - 4;
    const int b = gb >> 10, nb = (gb & 1023) << 2;
    if (t < 128) {
        const float inv = 1.f/(float)M1TOT;
        float mu  = g_sum1[t]*inv;
        float var = g_sq1[t]*inv - mu*mu;
        float sc  = gamma1[t]*rsqrtf(var + EPSBN);
        sm.g.scs[t] = sc; sm.g.shs[t] = beta1[t] - mu*sc;
    }
    __syncthreads();
    // load h1 tile, BN1+ReLU, write y to LDS [64][132]
    {
        const float* hsrc = g_h1 + (size_t)((b*NN + nb)*16)*128;
        const int ch0 = (4*t) & 127;
        float4 sc4 = *(const float4*)&sm.g.scs[ch0];
        float4 sh4 = *(const float4*)&sm.g.shs[ch0];
        #pragma unroll
        for (int j=0;j<8;j++){
            int f = j*1024 + 4*t;
            float4 v = *(const float4*)&hsrc[f];
            int s = f >> 7;
            float4 yv;
            yv.x = fmaxf(0.f, fmaf(v.x, sc4.x, sh4.x));
            yv.y = fmaxf(0.f, fmaf(v.y, sc4.y, sh4.y));
            yv.z = fmaxf(0.f, fmaf(v.z, sc4.z, sh4.z));
            yv.w = fmaxf(0.f, fmaf(v.w, sc4.w, sh4.w));
            *(float4*)&sm.g.yls[s*132 + ch0] = yv;
        }
    }
    const int cg = t & 15, sg = t >> 4, w = t >> 6;
    float acc2[4][8];
    #pragma unroll
    for (int r=0;r<4;r++)
        #pragma unroll
        for (int c=0;c<8;c++) acc2[r][c]=0.f;
    for (int kc = 0; kc < 4; ++kc) {
        for (int e = t; e < 4096; e += 256) {     // stage W2[:, kc*32..+32) transposed, split A/B
            int d = e >> 5, kk = e & 31;
            float wv = W2[(d << 7) + (kc<<5) + kk];
            int cgd = d >> 3, h = d & 7;
            if (h < 4) ((float*)&sm.g.w2A[kk*16 + cgd])[h]   = wv;
            else       ((float*)&sm.g.w2B[kk*16 + cgd])[h-4] = wv;
        }
        __syncthreads();
        #pragma unroll
        for (int c4=0;c4<8;c4++){
            float4 wA[4], wB[4];
            #pragma unroll
            for (int ii=0;ii<4;ii++){ wA[ii] = sm.g.w2A[(4*c4+ii)*16 + cg]; wB[ii] = sm.g.w2B[(4*c4+ii)*16 + cg]; }
            #pragma unroll
            for (int r=0;r<4;r++){
                float4 yv = *(const float4*)&sm.g.yls[((sg<<2)+r)*132 + (kc<<5) + (c4<<2)];
                #pragma unroll
                for (int ii=0;ii<4;ii++){
                    float y = (ii==0)?yv.x:(ii==1)?yv.y:(ii==2)?yv.z:yv.w;
                    acc2[r][0] = fmaf(y, wA[ii].x, acc2[r][0]);
                    acc2[r][1] = fmaf(y, wA[ii].y, acc2[r][1]);
                    acc2[r][2] = fmaf(y, wA[ii].z, acc2[r][2]);
                    acc2[r][3] = fmaf(y, wA[ii].w, acc2[r][3]);
                    acc2[r][4] = fmaf(y, wB[ii].x, acc2[r][4]);
                    acc2[r][5] = fmaf(y, wB[ii].y, acc2[r][5]);
                    acc2[r][6] = fmaf(y, wB[ii].z, acc2[r][6]);
                    acc2[r][7] = fmaf(y, wB[ii].w, acc2[r][7]);
                }
            }
        }
        __syncthreads();
    }
    // epilogue: h2 = acc2 + b2 ; stats2 ; per-NODE min/max over 16 neighbors
    const int node = nb + (sg >> 2);
    #pragma unroll
    for (int c=0;c<8;c++){
        const int ch = (cg<<3)+c;
        const float bb = b2[ch];
        float ls=0.f, lq=0.f, mn=3e38f, mx=-3e38f;
        #pragma unroll
        for (int r=0;r<4;r++){
            float h2 = acc2[r][c] + bb;
            ls += h2; lq = fmaf(h2,h2,lq);
            mn = fminf(mn,h2); mx = fmaxf(mx,h2);
        }
        ls += __shfl_xor(ls,16); ls += __shfl_xor(ls,32);
        lq += __shfl_xor(lq,16); lq += __shfl_xor(lq,32);
        if ((sg & 3) == 0) { sm.g.redS[w*128 + ch] = ls; sm.g.redQ[w*128 + ch] = lq; }
        float o;
        o = __shfl_xor(mn,16); mn = fminf(mn,o);
        o = __shfl_xor(mn,32); mn = fminf(mn,o);
        o = __shfl_xor(mx,16); mx = fmaxf(mx,o);
        o = __shfl_xor(mx,32); mx = fmaxf(mx,o);
        if ((sg & 3) == 0) {
            const int oo = ((b<<12)+node)*128 + ch;
            g_hminN[oo] = mn; g_hmaxN[oo] = mx;
        }
    }
    __syncthreads();
    if (t < 128) {
        float s = sm.g.redS[t] + sm.g.redS[128+t] + sm.g.redS[256+t] + sm.g.redS[384+t];
        float q = sm.g.redQ[t] + sm.g.redQ[128+t] + sm.g.redQ[256+t] + sm.g.redQ[384+t];
        atomicAdd(&g_sum2[t], s);
        atomicAdd(&g_sq2[t], q);
    }
}

// ================= kFinal: gather centroid nodes, BN2 affine + ReLU via min/max monotonicity ==
__global__ __launch_bounds__(256) void kFinal(const float* __restrict__ gamma2, const float* __restrict__ beta2,
                                              float* __restrict__ out)
{
    const int gid = blockIdx.x*256 + threadIdx.x;
    const int base = gid << 2;
    const int sl = base >> 7;                 // global slot 0..4095
    const int b = sl >> 10, slot = sl & 1023;
    const int ch0 = base & 127;
    const int node = g_cent[b][slot];
    const int src = ((b<<12)+node)*128 + ch0;
    const float inv = 1.f/(float)M1TOT;
    float4 mx = *(const float4*)&g_hmaxN[src];
    float4 mn = *(const float4*)&g_hminN[src];
    float4 o;
    #pragma unroll
    for (int c=0;c<4;c++){
        int ch = ch0 + c;
        float mu = g_sum2[ch]*inv, var = g_sq2[ch]*inv - mu*mu;
        float sc = gamma2[ch]*rsqrtf(var+EPSBN), sh = beta2[ch] - mu*sc;
        float hi = (c==0)?mx.x:(c==1)?mx.y:(c==2)?mx.z:mx.w;
        float lo = (c==0)?mn.x:(c==1)?mn.y:(c==2)?mn.z:mn.w;
        float v = fmaxf(0.f, fmaf((sc >= 0.f) ? hi : lo, sc, sh));
        if (c==0) o.x=v; else if (c==1) o.y=v; else if (c==2) o.z=v; else o.w=v;
    }
    *(float4*)&out[12288 + base] = o;
}

extern "C" void kernel_launch(void* const* d_in, const int* in_sizes, int n_in,
                              void* d_out, int out_size, void* d_ws, size_t ws_size,
                              hipStream_t stream)
{
    (void)in_sizes; (void)n_in; (void)d_ws; (void)ws_size; (void)out_size;
    const float* feat = (const float*)d_in[0];
    const float* pos  = (const float*)d_in[1];
    const float* W1   = (const float*)d_in[2];
    const float* b1   = (const float*)d_in[3];
    const float* g1   = (const float*)d_in[4];
    const float* be1  = (const float*)d_in[5];
    const float* W2   = (const float*)d_in[6];
    const float* b2   = (const float*)d_in[7];
    const float* g2   = (const float*)d_in[8];
    const float* be2  = (const float*)d_in[9];
    float* out = (float*)d_out;

    kPre  <<<dim3(37),   dim3(256), 0, stream>>>(pos);
    kS1   <<<dim3(4100), dim3(256), 0, stream>>>(feat, pos, W1, b1);
    kS2   <<<dim3(4100), dim3(256), 0, stream>>>(pos, out, W2, b2, g1, be1);
    kFinal<<<dim3(512),  dim3(256), 0, stream>>>(g2, be2, out);
}

// Round 8
// 2243.773 us; speedup vs baseline: 1.8431x; 1.8431x over previous
//
#include <hip/hip_runtime.h>

typedef float f2 __attribute__((ext_vector_type(2)));

#define NB 4
#define NN 4096
#define KNB 16
#define NS 1024
#define M1TOT (NB*NN*KNB)   // 262144
#define EPSBN 1e-5f
#define FPS_SPLIT 511       // kS1 runs iters [0,511); kS2 runs [511,1023)

// ---- module-scope scratch (fully rewritten every call; no ws_size assumption)
__device__ __align__(16) float g_h1[(size_t)M1TOT*128];   // 134 MB spilled layer-1 pre-activations
__device__ __align__(16) int   g_nbr[NB*NN*KNB];
__device__ __align__(16) float g_fps_rd[NB][NN];
__device__ unsigned g_fps_sel[NB][256];
__device__ int   g_fps_last[NB];
__device__ int   g_cent[NB][NS];
__device__ float g_sum1[128], g_sq1[128], g_sum2[128], g_sq2[128];
__device__ __align__(16) float g_hminN[NB*NN*128];        // 8 MB per-node h2 min
__device__ __align__(16) float g_hmaxN[NB*NN*128];        // 8 MB per-node h2 max

struct __align__(16) FpsSm {
    float spx[NN], spy[NN], spz[NN];
    float sv[2][4]; int sj[2][4];
    int   cnts[256];
};
struct __align__(16) G1Sm {
    float  xls[64*68];
    float4 wlsA[68*16], wlsB[68*16];
    float  redS[512], redQ[512];
};
struct __align__(16) G2Sm {
    float  yls[64*132];
    float4 w2A[32*16], w2B[32*16];
    float  scs[128], shs[128];
    float  redS[512], redQ[512];
};

// ================= FPS chunk: 256 threads, 16 pts/thread (f2 packed), checkpointed ==========
__device__ __forceinline__ void fps_chunk(const float* __restrict__ pos, float* __restrict__ out,
                                          FpsSm* sm, int b, int t, int it0, int it1,
                                          bool first, bool last)
{
#pragma clang fp contract(off)
    const float* pb = pos + b*NN*3;
    for (int i = t; i < NN; i += 256) { sm->spx[i]=pb[3*i]; sm->spy[i]=pb[3*i+1]; sm->spz[i]=pb[3*i+2]; }
    __syncthreads();
    f2 rx[8], ry[8], rz[8], rd[8];
    #pragma unroll
    for (int p=0;p<8;p++){
        int j = (t<<4) + 2*p;
        rx[p] = *(const f2*)&sm->spx[j];
        ry[p] = *(const f2*)&sm->spy[j];
        rz[p] = *(const f2*)&sm->spz[j];
    }
    unsigned sel; int j2;
    if (first) {
        #pragma unroll
        for (int p=0;p<8;p++) rd[p] = (f2){1e10f, 1e10f};
        sel = (t==0) ? 1u : 0u;              // node 0 is always selected
        j2 = 0;
    } else {
        #pragma unroll
        for (int u=0;u<4;u++){
            float4 ld = *(const float4*)&g_fps_rd[b][(t<<4)+(u<<2)];
            rd[2*u]   = (f2){ld.x, ld.y};
            rd[2*u+1] = (f2){ld.z, ld.w};
        }
        sel = g_fps_sel[b][t];
        j2  = g_fps_last[b];
    }
    float cx = sm->spx[j2], cy = sm->spy[j2], cz = sm->spz[j2];

    for (int it = it0; it < it1; ++it) {
        const int par = it & 1;
        const f2 c2x = {cx,cx}, c2y = {cy,cy}, c2z = {cz,cz};
        #pragma unroll
        for (int p=0;p<8;p++){
            f2 dx = rx[p]-c2x, dy = ry[p]-c2y, dz = rz[p]-c2z;
            f2 m0 = dx*dx, m1 = dy*dy, m2 = dz*dz;
            f2 a0 = m0 + m1;
            f2 d  = a0 + m2;                 // exact (dx^2+dy^2)+dz^2, contract off
            rd[p] = __builtin_elementwise_min(rd[p], d);
        }
        // local max tree (packed)
        f2 t0 = __builtin_elementwise_max(rd[0], rd[1]);
        f2 t1 = __builtin_elementwise_max(rd[2], rd[3]);
        f2 t2 = __builtin_elementwise_max(rd[4], rd[5]);
        f2 t3 = __builtin_elementwise_max(rd[6], rd[7]);
        t0 = __builtin_elementwise_max(t0, t1);
        t2 = __builtin_elementwise_max(t2, t3);
        t0 = __builtin_elementwise_max(t0, t2);
        float wv = fmaxf(t0.x, t0.y);
        // wave max, value only (6 cross-lane ops)
        #pragma unroll
        for (int m=1;m<64;m<<=1) wv = fmaxf(wv, __shfl_xor(wv, m));
        // lowest local index equal to wave max (reverse scan -> lowest wins)
        int lj = 0x7fffffff;
        #pragma unroll
        for (int p=7;p>=0;p--){
            lj = (rd[p].y == wv) ? ((t<<4)+2*p+1) : lj;
            lj = (rd[p].x == wv) ? ((t<<4)+2*p)   : lj;
        }
        // lanes cover ascending index ranges: first matching lane = lowest global index
        unsigned long long mk = __ballot(lj != 0x7fffffff);
        int src = __ffsll(mk) - 1;
        int bj = __shfl(lj, src);
        if ((t & 63) == 0) { sm->sv[par][t>>6] = wv; sm->sj[par][t>>6] = bj; }
        __syncthreads();     // single barrier/iter; parity double-buffered slots
        float v = sm->sv[par][0]; int jn = sm->sj[par][0];
        #pragma unroll
        for (int w=1;w<4;w++){
            float ov = sm->sv[par][w]; int oj = sm->sj[par][w];
            if (ov > v || (ov == v && oj < jn)) { v = ov; jn = oj; }
        }
        j2 = jn;
        cx = sm->spx[j2]; cy = sm->spy[j2]; cz = sm->spz[j2];
        unsigned rel = (unsigned)(j2 - (t<<4));
        if (rel < 16u) sel |= (1u << rel);
    }

    if (!last) {
        #pragma unroll
        for (int u=0;u<4;u++){
            float4 st = {rd[2*u].x, rd[2*u].y, rd[2*u+1].x, rd[2*u+1].y};
            *(float4*)&g_fps_rd[b][(t<<4)+(u<<2)] = st;
        }
        g_fps_sel[b][t] = sel;
        if (t == 0) g_fps_last[b] = j2;
    } else {
        // ordered compaction (ascending node index == reference's sorted centroids)
        sm->cnts[t] = (int)__popc(sel);
        __syncthreads();
        if (t == 0) { int run = 0; for (int i=0;i<256;i++){ int c = sm->cnts[i]; sm->cnts[i] = run; run += c; } }
        __syncthreads();
        int base = sm->cnts[t];
        #pragma unroll
        for (int i=0;i<16;i++){
            int j = (t<<4)+i;
            if (sel & (1u<<i)) {
                g_cent[b][base] = j;
                float* po = out + (size_t)((b<<10)+base)*3;
                po[0]=sm->spx[j]; po[1]=sm->spy[j]; po[2]=sm->spz[j];
                base++;
            }
        }
    }
}

// ================= kPre: blocks 0-63 KNN (1 query/thread), block 64 stat-zero ===============
__global__ __launch_bounds__(256, 1) void kPre(const float* __restrict__ pos)
{
    __shared__ float spx[NN], spy[NN], spz[NN];
    const int blk = blockIdx.x, t = threadIdx.x;
    if (blk >= 64) {
        if (t < 128) { g_sum1[t]=0.f; g_sq1[t]=0.f; g_sum2[t]=0.f; g_sq2[t]=0.f; }
        return;
    }
    const int b = blk >> 4;
    const int q = ((blk & 15) << 8) + t;
    const float* pb = pos + b*NN*3;
    for (int i = t; i < NN; i += 256) { spx[i]=pb[3*i]; spy[i]=pb[3*i+1]; spz[i]=pb[3*i+2]; }
    __syncthreads();
    const float qx = spx[q], qy = spy[q], qz = spz[q];
    float bd[16]; int bi[16];
    #pragma unroll
    for (int u=0;u<16;u++){ bd[u]=3e38f; bi[u]=0; }
    float wmax = 3e38f;
    for (int j = 0; j < NN; ++j) {
        float dx = spx[j]-qx, dy = spy[j]-qy, dz = spz[j]-qz;
        float d = __fadd_rn(__fadd_rn(__fmul_rn(dx,dx),__fmul_rn(dy,dy)),__fmul_rn(dz,dz));
        if (d < wmax) {                      // strict <: lowest index wins boundary ties
            float m0 = bd[0]; int mj = 0;
            #pragma unroll
            for (int u=1;u<16;u++){ if (bd[u] > m0) { m0 = bd[u]; mj = u; } }
            #pragma unroll
            for (int u=0;u<16;u++){ if (u == mj) { bd[u] = d; bi[u] = j; } }
            wmax = bd[0];
            #pragma unroll
            for (int u=1;u<16;u++) wmax = fmaxf(wmax, bd[u]);
        }
    }
    int* dst = g_nbr + ((size_t)(b*NN + q) << 4);
    #pragma unroll
    for (int u=0;u<16;u++) dst[u] = bi[u];
}

// ================= kS1: blocks 0-3 FPS [0,511); blocks 4..4099 GEMM1 + stats + h1 spill =====
__global__ __launch_bounds__(256, 1) void kS1(const float* __restrict__ feat, const float* __restrict__ pos,
                                              const float* __restrict__ W1, const float* __restrict__ b1)
{
    __shared__ union { FpsSm f; G1Sm g; } sm;
    const int blk = blockIdx.x, t = threadIdx.x;
    if (blk < 4) { fps_chunk(pos, nullptr, &sm.f, blk, t, 0, FPS_SPLIT, true, false); return; }
    const int gb = blk - 4;
    const int b = gb >> 10, nb = (gb & 1023) << 2;

    // stage W1 -> two float4 arrays [row 0..67][cg], row permuted (feat 0..63, rel 64..66, 67 zero)
    for (int e = t; e < 128*67; e += 256) {
        int co = e / 67, ci = e - co*67;
        int row = (ci < 3) ? (64 + ci) : (ci - 3);
        int cgd = co >> 3, h = co & 7;
        float w = W1[e];
        if (h < 4) ((float*)&sm.g.wlsA[row*16 + cgd])[h]   = w;
        else       ((float*)&sm.g.wlsB[row*16 + cgd])[h-4] = w;
    }
    if (t < 64) { ((float*)&sm.g.wlsA[67*16])[t] = 0.f; ((float*)&sm.g.wlsB[67*16])[t] = 0.f; }
    // gather x: 64 samples (4 nodes x 16 nbrs) x 68
    {
        const int s = t >> 2, h = t & 3;
        const int n = nb + (s >> 4), k = s & 15;
        const int gq = b*NN + n;
        const int idx = g_nbr[(gq << 4) + k];
        const float* fr = feat + ((size_t)(b*NN + idx) << 6) + (h << 4);
        float* xr = sm.g.xls + s*68 + (h << 4);
        #pragma unroll
        for (int u=0;u<4;u++) ((float4*)xr)[u] = ((const float4*)fr)[u];
        if (h == 0) {
            const float* pn = pos + (size_t)gq*3;
            const float* pi = pos + (size_t)(b*NN + idx)*3;
            sm.g.xls[s*68 + 64] = pi[0]-pn[0];
            sm.g.xls[s*68 + 65] = pi[1]-pn[1];
            sm.g.xls[s*68 + 66] = pi[2]-pn[2];
            sm.g.xls[s*68 + 67] = 0.f;
        }
    }
    __syncthreads();
    const int cg = t & 15, sg = t >> 4, w = t >> 6;
    float acc[4][8];
    #pragma unroll
    for (int r=0;r<4;r++)
        #pragma unroll
        for (int c=0;c<8;c++) acc[r][c] = 0.f;
    for (int c4 = 0; c4 < 17; ++c4) {
        float4 wA[4], wB[4];
        #pragma unroll
        for (int ii=0;ii<4;ii++){ wA[ii] = sm.g.wlsA[(4*c4+ii)*16 + cg]; wB[ii] = sm.g.wlsB[(4*c4+ii)*16 + cg]; }
        #pragma unroll
        for (int r=0;r<4;r++){
            float4 xv = *(const float4*)&sm.g.xls[(sg + (r<<4))*68 + (c4<<2)];
            #pragma unroll
            for (int ii=0;ii<4;ii++){
                float x = (ii==0)?xv.x:(ii==1)?xv.y:(ii==2)?xv.z:xv.w;
                acc[r][0] = fmaf(x, wA[ii].x, acc[r][0]);
                acc[r][1] = fmaf(x, wA[ii].y, acc[r][1]);
                acc[r][2] = fmaf(x, wA[ii].z, acc[r][2]);
                acc[r][3] = fmaf(x, wA[ii].w, acc[r][3]);
                acc[r][4] = fmaf(x, wB[ii].x, acc[r][4]);
                acc[r][5] = fmaf(x, wB[ii].y, acc[r][5]);
                acc[r][6] = fmaf(x, wB[ii].z, acc[r][6]);
                acc[r][7] = fmaf(x, wB[ii].w, acc[r][7]);
            }
        }
    }
    // h1 = acc + b1 ; stats ; spill to g_h1
    float4 bA = *(const float4*)&b1[cg<<3];
    float4 bB = *(const float4*)&b1[(cg<<3)+4];
    float h1v[4][8];
    #pragma unroll
    for (int r=0;r<4;r++){
        h1v[r][0]=acc[r][0]+bA.x; h1v[r][1]=acc[r][1]+bA.y; h1v[r][2]=acc[r][2]+bA.z; h1v[r][3]=acc[r][3]+bA.w;
        h1v[r][4]=acc[r][4]+bB.x; h1v[r][5]=acc[r][5]+bB.y; h1v[r][6]=acc[r][6]+bB.z; h1v[r][7]=acc[r][7]+bB.w;
    }
    #pragma unroll
    for (int c=0;c<8;c++){
        const int ch = (cg<<3)+c;
        float ls=0.f, lq=0.f;
        #pragma unroll
        for (int r=0;r<4;r++){ float h1 = h1v[r][c]; ls += h1; lq = fmaf(h1,h1,lq); }
        ls += __shfl_xor(ls,16); ls += __shfl_xor(ls,32);
        lq += __shfl_xor(lq,16); lq += __shfl_xor(lq,32);
        if ((sg & 3) == 0) { sm.g.redS[w*128 + ch] = ls; sm.g.redQ[w*128 + ch] = lq; }
    }
    #pragma unroll
    for (int r=0;r<4;r++){
        const int gs = (b*NN + nb + r)*16 + sg;
        float4 o0 = {h1v[r][0],h1v[r][1],h1v[r][2],h1v[r][3]};
        float4 o1 = {h1v[r][4],h1v[r][5],h1v[r][6],h1v[r][7]};
        *(float4*)&g_h1[(size_t)gs*128 + (cg<<3)]     = o0;
        *(float4*)&g_h1[(size_t)gs*128 + (cg<<3) + 4] = o1;
    }
    __syncthreads();
    if (t < 128) {
        float s = sm.g.redS[t] + sm.g.redS[128+t] + sm.g.redS[256+t] + sm.g.redS[384+t];
        float q = sm.g.redQ[t] + sm.g.redQ[128+t] + sm.g.redQ[256+t] + sm.g.redQ[384+t];
        atomicAdd(&g_sum1[t], s);
        atomicAdd(&g_sq1[t], q);
    }
}

// ================= kS2: blocks 0-3 FPS [511,1023)+finish; blocks 4..4099 BN1+GEMM2 ==========
__global__ __launch_bounds__(256, 1) void kS2(const float* __restrict__ pos, float* __restrict__ out,
        const float* __restrict__ W2, const float* __restrict__ b2,
        const float* __restrict__ gamma1, const float* __restrict__ beta1)
{
    __shared__ union { FpsSm f; G2Sm g; } sm;
    const int blk = blockIdx.x, t = threadIdx.x;
    if (blk < 4) { fps_chunk(pos, out, &sm.f, blk, t, FPS_SPLIT, NS-1, false, true); return; }
    const int gb = blk - 4;
    const int b = gb >> 10, nb = (gb & 1023) << 2;
    if (t < 128) {
        const float inv = 1.f/(float)M1TOT;
        float mu  = g_sum1[t]*inv;
        float var = g_sq1[t]*inv - mu*mu;
        float sc  = gamma1[t]*rsqrtf(var + EPSBN);
        sm.g.scs[t] = sc; sm.g.shs[t] = beta1[t] - mu*sc;
    }
    __syncthreads();
    // load h1 tile, BN1+ReLU, write y to LDS [64][132]
    {
        const float* hsrc = g_h1 + (size_t)((b*NN + nb)*16)*128;
        const int ch0 = (4*t) & 127;
        float4 sc4 = *(const float4*)&sm.g.scs[ch0];
        float4 sh4 = *(const float4*)&sm.g.shs[ch0];
        #pragma unroll
        for (int j=0;j<8;j++){
            int f = j*1024 + 4*t;
            float4 v = *(const float4*)&hsrc[f];
            int s = f >> 7;
            float4 yv;
            yv.x = fmaxf(0.f, fmaf(v.x, sc4.x, sh4.x));
            yv.y = fmaxf(0.f, fmaf(v.y, sc4.y, sh4.y));
            yv.z = fmaxf(0.f, fmaf(v.z, sc4.z, sh4.z));
            yv.w = fmaxf(0.f, fmaf(v.w, sc4.w, sh4.w));
            *(float4*)&sm.g.yls[s*132 + ch0] = yv;
        }
    }
    const int cg = t & 15, sg = t >> 4, w = t >> 6;
    float acc2[4][8];
    #pragma unroll
    for (int r=0;r<4;r++)
        #pragma unroll
        for (int c=0;c<8;c++) acc2[r][c]=0.f;
    for (int kc = 0; kc < 4; ++kc) {
        for (int e = t; e < 4096; e += 256) {     // stage W2[:, kc*32..+32) transposed, split A/B
            int d = e >> 5, kk = e & 31;
            float wv = W2[(d << 7) + (kc<<5) + kk];
            int cgd = d >> 3, h = d & 7;
            if (h < 4) ((float*)&sm.g.w2A[kk*16 + cgd])[h]   = wv;
            else       ((float*)&sm.g.w2B[kk*16 + cgd])[h-4] = wv;
        }
        __syncthreads();
        #pragma unroll
        for (int c4=0;c4<8;c4++){
            float4 wA[4], wB[4];
            #pragma unroll
            for (int ii=0;ii<4;ii++){ wA[ii] = sm.g.w2A[(4*c4+ii)*16 + cg]; wB[ii] = sm.g.w2B[(4*c4+ii)*16 + cg]; }
            #pragma unroll
            for (int r=0;r<4;r++){
                float4 yv = *(const float4*)&sm.g.yls[((sg<<2)+r)*132 + (kc<<5) + (c4<<2)];
                #pragma unroll
                for (int ii=0;ii<4;ii++){
                    float y = (ii==0)?yv.x:(ii==1)?yv.y:(ii==2)?yv.z:yv.w;
                    acc2[r][0] = fmaf(y, wA[ii].x, acc2[r][0]);
                    acc2[r][1] = fmaf(y, wA[ii].y, acc2[r][1]);
                    acc2[r][2] = fmaf(y, wA[ii].z, acc2[r][2]);
                    acc2[r][3] = fmaf(y, wA[ii].w, acc2[r][3]);
                    acc2[r][4] = fmaf(y, wB[ii].x, acc2[r][4]);
                    acc2[r][5] = fmaf(y, wB[ii].y, acc2[r][5]);
                    acc2[r][6] = fmaf(y, wB[ii].z, acc2[r][6]);
                    acc2[r][7] = fmaf(y, wB[ii].w, acc2[r][7]);
                }
            }
        }
        __syncthreads();
    }
    // epilogue: h2 = acc2 + b2 ; stats2 ; per-NODE min/max over 16 neighbors
    const int node = nb + (sg >> 2);
    #pragma unroll
    for (int c=0;c<8;c++){
        const int ch = (cg<<3)+c;
        const float bb = b2[ch];
        float ls=0.f, lq=0.f, mn=3e38f, mx=-3e38f;
        #pragma unroll
        for (int r=0;r<4;r++){
            float h2 = acc2[r][c] + bb;
            ls += h2; lq = fmaf(h2,h2,lq);
            mn = fminf(mn,h2); mx = fmaxf(mx,h2);
        }
        ls += __shfl_xor(ls,16); ls += __shfl_xor(ls,32);
        lq += __shfl_xor(lq,16); lq += __shfl_xor(lq,32);
        if ((sg & 3) == 0) { sm.g.redS[w*128 + ch] = ls; sm.g.redQ[w*128 + ch] = lq; }
        float o;
        o = __shfl_xor(mn,16); mn = fminf(mn,o);
        o = __shfl_xor(mn,32); mn = fminf(mn,o);
        o = __shfl_xor(mx,16); mx = fmaxf(mx,o);
        o = __shfl_xor(mx,32); mx = fmaxf(mx,o);
        if ((sg & 3) == 0) {
            const int oo = ((b<<12)+node)*128 + ch;
            g_hminN[oo] = mn; g_hmaxN[oo] = mx;
        }
    }
    __syncthreads();
    if (t < 128) {
        float s = sm.g.redS[t] + sm.g.redS[128+t] + sm.g.redS[256+t] + sm.g.redS[384+t];
        float q = sm.g.redQ[t] + sm.g.redQ[128+t] + sm.g.redQ[256+t] + sm.g.redQ[384+t];
        atomicAdd(&g_sum2[t], s);
        atomicAdd(&g_sq2[t], q);
    }
}

// ================= kFinal: gather centroid nodes, BN2 affine + ReLU via min/max monotonicity ==
__global__ __launch_bounds__(256) void kFinal(const float* __restrict__ gamma2, const float* __restrict__ beta2,
                                              float* __restrict__ out)
{
    const int gid = blockIdx.x*256 + threadIdx.x;
    const int base = gid << 2;
    const int sl = base >> 7;                 // global slot 0..4095
    const int b = sl >> 10, slot = sl & 1023;
    const int ch0 = base & 127;
    const int node = g_cent[b][slot];
    const int src = ((b<<12)+node)*128 + ch0;
    const float inv = 1.f/(float)M1TOT;
    float4 mx = *(const float4*)&g_hmaxN[src];
    float4 mn = *(const float4*)&g_hminN[src];
    float4 o;
    #pragma unroll
    for (int c=0;c<4;c++){
        int ch = ch0 + c;
        float mu = g_sum2[ch]*inv, var = g_sq2[ch]*inv - mu*mu;
        float sc = gamma2[ch]*rsqrtf(var+EPSBN), sh = beta2[ch] - mu*sc;
        float hi = (c==0)?mx.x:(c==1)?mx.y:(c==2)?mx.z:mx.w;
        float lo = (c==0)?mn.x:(c==1)?mn.y:(c==2)?mn.z:mn.w;
        float v = fmaxf(0.f, fmaf((sc >= 0.f) ? hi : lo, sc, sh));
        if (c==0) o.x=v; else if (c==1) o.y=v; else if (c==2) o.z=v; else o.w=v;
    }
    *(float4*)&out[12288 + base] = o;
}

extern "C" void kernel_launch(void* const* d_in, const int* in_sizes, int n_in,
                              void* d_out, int out_size, void* d_ws, size_t ws_size,
                              hipStream_t stream)
{
    (void)in_sizes; (void)n_in; (void)d_ws; (void)ws_size; (void)out_size;
    const float* feat = (const float*)d_in[0];
    const float* pos  = (const float*)d_in[1];
    const float* W1   = (const float*)d_in[2];
    const float* b1   = (const float*)d_in[3];
    const float* g1   = (const float*)d_in[4];
    const float* be1  = (const float*)d_in[5];
    const float* W2   = (const float*)d_in[6];
    const float* b2   = (const float*)d_in[7];
    const float* g2   = (const float*)d_in[8];
    const float* be2  = (const float*)d_in[9];
    float* out = (float*)d_out;

    kPre  <<<dim3(65),   dim3(256), 0, stream>>>(pos);
    kS1   <<<dim3(4100), dim3(256), 0, stream>>>(feat, pos, W1, b1);
    kS2   <<<dim3(4100), dim3(256), 0, stream>>>(pos, out, W2, b2, g1, be1);
    kFinal<<<dim3(512),  dim3(256), 0, stream>>>(g2, be2, out);
}